// Round 10
// baseline (2348.806 us; speedup 1.0000x reference)
//
#include <hip/hip_runtime.h>
#include <hip/hip_bf16.h>
#include <math.h>

constexpr int B = 32;
constexpr int N = 2048;

// ---------------------------------------------------------------------------
// dtype sniffer: bf16 vs fp32 (validated rounds 1-9).
// ---------------------------------------------------------------------------
__global__ void detect_kernel(const unsigned int* __restrict__ raw, int* __restrict__ flag) {
    __shared__ int cnt;
    if (threadIdx.x == 0) cnt = 0;
    __syncthreads();
    int c = 0;
    for (int i = threadIdx.x; i < 4096; i += 256) {
        unsigned h = (raw[i] >> 8) & 0x7f;
        if (h >= 0x3a && h <= 0x41) c++;
    }
    atomicAdd(&cnt, c);
    __syncthreads();
    if (threadIdx.x == 0) *flag = (cnt > (4096 * 55) / 100) ? 1 : 0;
}

struct ConvSeg { const void* src; float* dst; int n; };
struct ConvParams { ConvSeg s[15]; };

__global__ void convert_kernel(ConvParams p, const int* __restrict__ flag) {
    const ConvSeg sg = p.s[blockIdx.y];
    int i = blockIdx.x * 256 + threadIdx.x;
    if (i >= sg.n) return;
    if (*flag) sg.dst[i] = __bfloat162float(((const __hip_bfloat16*)sg.src)[i]);
    else       sg.dst[i] = ((const float*)sg.src)[i];
}

// ---------------------------------------------------------------------------
// KNN (round-1 verbatim): k smallest (d2, idx) lexicographic == stable top_k.
// ---------------------------------------------------------------------------
template <int K>
__global__ void __launch_bounds__(256) knn_kernel(const float* __restrict__ pos,
                                                  int* __restrict__ idx_out, int n) {
    #pragma clang fp contract(off)
    const int b = blockIdx.y;
    const int i = blockIdx.x * 256 + threadIdx.x;
    const float* pb = pos + (size_t)b * n * 3;
    const float xi = pb[i * 3 + 0], yi = pb[i * 3 + 1], zi = pb[i * 3 + 2];

    float bd[K];
    int   bi_[K];
    #pragma unroll
    for (int q = 0; q < K; ++q) { bd[q] = __builtin_inff(); bi_[q] = 0x7fffffff; }

    __shared__ float tx[256], ty[256], tz[256];
    for (int t0 = 0; t0 < n; t0 += 256) {
        __syncthreads();
        {
            int j = t0 + threadIdx.x;
            tx[threadIdx.x] = pb[j * 3 + 0];
            ty[threadIdx.x] = pb[j * 3 + 1];
            tz[threadIdx.x] = pb[j * 3 + 2];
        }
        __syncthreads();
        for (int jj = 0; jj < 256; ++jj) {
            float dx = xi - tx[jj], dy = yi - ty[jj], dz = zi - tz[jj];
            float d2 = (dx * dx + dy * dy) + dz * dz;
            int jg = t0 + jj;
            if (d2 < bd[K - 1] || (d2 == bd[K - 1] && jg < bi_[K - 1])) {
                bd[K - 1] = d2; bi_[K - 1] = jg;
                #pragma unroll
                for (int q = K - 1; q > 0; --q) {
                    bool sw = (bd[q] < bd[q - 1]) || (bd[q] == bd[q - 1] && bi_[q] < bi_[q - 1]);
                    if (sw) {
                        float td = bd[q]; bd[q] = bd[q - 1]; bd[q - 1] = td;
                        int   ti = bi_[q]; bi_[q] = bi_[q - 1]; bi_[q - 1] = ti;
                    }
                }
            }
        }
    }
    int* op = idx_out + ((size_t)b * n + i) * K;
    #pragma unroll
    for (int q = 0; q < K; ++q) op[q] = bi_[q];
}

// ---------------------------------------------------------------------------
// Wave-64 max reduce via DPP (pure VALU).
// ---------------------------------------------------------------------------
#define DPP_MAXF(v, ctrl)                                                      \
    (v) = fmaxf((v), __int_as_float(__builtin_amdgcn_update_dpp(               \
        __float_as_int(v), __float_as_int(v), (ctrl), 0xf, 0xf, false)))

// ---------------------------------------------------------------------------
// FPS phase in LDS — round-6 logic (proven 651us @ NT=256) with ONE change:
// the per-iteration __syncthreads is replaced by a sense-reversing spin-poll.
// Each wave's lane 0 writes its candidate key, then release-stores seq = it;
// all waves acquire-poll the 4 seq words (independent LDS loads, one
// overlapped round-trip) and fold. Parity double-buffering bounds wave skew
// to 1 iteration: a wave reaches it+1 only after ALL waves wrote their it
// slot, which each wave does only after consuming it-1 -> overwriting the
// (it-1)-parity slot at it+1 is safe. Results are timing-independent
// (fold sees exact values). Exact jnp.argmax semantics, contract-off
// distances, key=(d2<<32)|~idx (max key == max d2, tie -> lowest idx).
// ---------------------------------------------------------------------------
template <int NPTS>
__device__ __forceinline__ void fps_phase(const float* __restrict__ px,
                                          const float* __restrict__ py,
                                          const float* __restrict__ pz,
                                          int* __restrict__ sel_lds,
                                          unsigned long long* __restrict__ slots,
                                          unsigned* __restrict__ seq,
                                          int m, int t) {
    #pragma clang fp contract(off)
    constexpr int P = NPTS / 256;
    float d[P], ox[P], oy[P], oz[P];
    #pragma unroll
    for (int p = 0; p < P; ++p) {
        const int ii = t * P + p;
        ox[p] = px[ii]; oy[p] = py[ii]; oz[p] = pz[ii];
        d[p] = __builtin_inff();     // iteration 1 update vs point 0 == ref init
    }
    if (t == 0) sel_lds[0] = 0;
    float nx = px[0], ny = py[0], nz = pz[0];

    for (int it = 1; it < m; ++it) {
        float bv = -1.0f; int bix = 0;
        #pragma unroll
        for (int p = 0; p < P; ++p) {
            float dx = ox[p] - nx, dy = oy[p] - ny, dz = oz[p] - nz;
            float dd = (dx * dx + dy * dy) + dz * dz;
            float dn = fminf(d[p], dd);
            d[p] = dn;
            if (dn > bv) { bv = dn; bix = t * P + p; }   // strict > keeps lowest idx
        }
        // wave max (value only, VALU DPP chain)
        float r = bv;
        DPP_MAXF(r, 0x111); DPP_MAXF(r, 0x112); DPP_MAXF(r, 0x114);
        DPP_MAXF(r, 0x118); DPP_MAXF(r, 0x142); DPP_MAXF(r, 0x143);
        const float gmax = __int_as_float(__builtin_amdgcn_readlane(__float_as_int(r), 63));
        // index resolve: lowest lane with bv == gmax == lowest global index
        const unsigned long long msk = __ballot(bv == gmax);
        const int wl = (int)__builtin_ctzll(msk);
        const int widx = __builtin_amdgcn_readlane(bix, wl);
        const int base = (it & 1) * 4;
        if ((t & 63) == 0) {
            slots[base + (t >> 6)] =
                ((unsigned long long)(unsigned)__float_as_int(gmax) << 32) |
                (unsigned)(~widx);
            __hip_atomic_store(&seq[base + (t >> 6)], (unsigned)it,
                               __ATOMIC_RELEASE, __HIP_MEMORY_SCOPE_WORKGROUP);
        }
        // spin-poll: all 4 seq words in one overlapped round
        {
            unsigned s0, s1, s2, s3;
            const unsigned uit = (unsigned)it;
            do {
                s0 = __hip_atomic_load(&seq[base + 0], __ATOMIC_ACQUIRE, __HIP_MEMORY_SCOPE_WORKGROUP);
                s1 = __hip_atomic_load(&seq[base + 1], __ATOMIC_ACQUIRE, __HIP_MEMORY_SCOPE_WORKGROUP);
                s2 = __hip_atomic_load(&seq[base + 2], __ATOMIC_ACQUIRE, __HIP_MEMORY_SCOPE_WORKGROUP);
                s3 = __hip_atomic_load(&seq[base + 3], __ATOMIC_ACQUIRE, __HIP_MEMORY_SCOPE_WORKGROUP);
            } while (((s0 ^ uit) | (s1 ^ uit) | (s2 ^ uit) | (s3 ^ uit)) != 0);
        }
        const unsigned long long* sp = slots + base;
        unsigned long long k0 = sp[0], k1 = sp[1], k2 = sp[2], k3 = sp[3];
        if (k1 > k0) k0 = k1;
        if (k3 > k2) k2 = k3;
        const unsigned long long kb = (k2 > k0) ? k2 : k0;
        const int g = ~(int)(unsigned)(kb & 0xffffffffULL);
        if (t == 0) sel_lds[it] = g;
        nx = px[g]; ny = py[g]; nz = pz[g];
    }
    __syncthreads();
}

// ---------------------------------------------------------------------------
// FPS-only kernel: 32 blocks x 256 threads (measured optimum), isolated.
// ---------------------------------------------------------------------------
__global__ void __launch_bounds__(256) fps_only_kernel(
        const float* __restrict__ posf, int* __restrict__ sel1, int* __restrict__ sel2,
        float* __restrict__ p2, float* __restrict__ p3) {
    __shared__ float px[2048], py[2048], pz[2048];
    __shared__ float qx[1024], qy[1024], qz[1024];
    __shared__ int sel1_l[1024], sel2_l[512];
    __shared__ unsigned long long slots[8];
    __shared__ unsigned seq[8];
    const int t = threadIdx.x;
    const int b = blockIdx.x;

    const float* pb = posf + (size_t)b * N * 3;
    for (int i = t; i < N; i += 256) {
        px[i] = pb[i * 3 + 0]; py[i] = pb[i * 3 + 1]; pz[i] = pb[i * 3 + 2];
    }
    if (t < 8) seq[t] = 0;
    __syncthreads();

    fps_phase<2048>(px, py, pz, sel1_l, slots, seq, 1024, t);

    for (int i = t; i < 1024; i += 256) {
        int s = sel1_l[i];
        qx[i] = px[s]; qy[i] = py[s]; qz[i] = pz[s];
        sel1[(size_t)b * 1024 + i] = s;
    }
    if (t < 8) seq[t] = 0;          // fresh sense for phase 2
    __syncthreads();
    for (int i = t; i < 1024; i += 256) {
        float* pp = p2 + ((size_t)b * 1024 + i) * 3;
        pp[0] = qx[i]; pp[1] = qy[i]; pp[2] = qz[i];
    }

    fps_phase<1024>(qx, qy, qz, sel2_l, slots, seq, 512, t);

    for (int i = t; i < 512; i += 256) {
        int s = sel2_l[i];
        sel2[(size_t)b * 512 + i] = s;
        float* pp = p3 + ((size_t)b * 512 + i) * 3;
        pp[0] = qx[s]; pp[1] = qy[s]; pp[2] = qz[s];
    }
}

// ---------------------------------------------------------------------------
// PointNet layer 1 (round-1 verbatim): thread-per-point, LDS bounce so a[64]
// and o[64] never co-live -> ~108 VGPR, no spill (proven r1/r2/r6).
// ---------------------------------------------------------------------------
__global__ void __launch_bounds__(64) pointnet3_kernel(
        const float* __restrict__ pos, const int* __restrict__ idx,
        const float* __restrict__ W1, const float* __restrict__ b1,
        const float* __restrict__ W2, const float* __restrict__ b2,
        float* __restrict__ out, int n, int k) {
    const int b = blockIdx.y, lane = threadIdx.x;
    const int i = blockIdx.x * 64 + lane;
    const float* pb = pos + (size_t)b * n * 3;
    const float xi = pb[i * 3 + 0], yi = pb[i * 3 + 1], zi = pb[i * 3 + 2];

    __shared__ float a_lds[64 * 64];

    float acc[64];
    #pragma unroll
    for (int c = 0; c < 64; ++c) acc[c] = -__builtin_inff();

    const int* idxp = idx + ((size_t)b * n + i) * k;
    for (int kk = 0; kk < k; ++kk) {
        const int j = idxp[kk];
        const float xj = pb[j * 3 + 0], yj = pb[j * 3 + 1], zj = pb[j * 3 + 2];
        const float mv[9] = {xi, yi, zi, xj, yj, zj, xj - xi, yj - yi, zj - zi};
        float a[64];
        #pragma unroll
        for (int e = 0; e < 64; ++e) a[e] = b1[e];
        #pragma unroll
        for (int d = 0; d < 9; ++d) {
            #pragma unroll
            for (int e = 0; e < 64; ++e) a[e] = fmaf(mv[d], W1[d * 64 + e], a[e]);
        }
        __syncthreads();
        #pragma unroll
        for (int e = 0; e < 64; ++e) a_lds[e * 64 + lane] = fmaxf(a[e], 0.f);
        __syncthreads();
        float o[64];
        #pragma unroll
        for (int c = 0; c < 64; ++c) o[c] = b2[c];
        for (int e = 0; e < 64; ++e) {
            float av = a_lds[e * 64 + lane];
            #pragma unroll
            for (int c = 0; c < 64; ++c) o[c] = fmaf(av, W2[e * 64 + c], o[c]);
        }
        #pragma unroll
        for (int c = 0; c < 64; ++c) acc[c] = fmaxf(acc[c], o[c]);
    }
    float* op = out + ((size_t)b * n + i) * 64;
    #pragma unroll
    for (int c = 0; c < 64; ++c) op[c] = fmaxf(acc[c], 0.f);
}

// ---------------------------------------------------------------------------
// PointNet CHIN=64 (round-1 structure + sel indirection for h reads).
// ---------------------------------------------------------------------------
__global__ void __launch_bounds__(64) pointnet64_kernel(
        const float* __restrict__ h_base, const float* __restrict__ pos,
        const int* __restrict__ sel, const int* __restrict__ idx,
        const float* __restrict__ W1, const float* __restrict__ b1,
        const float* __restrict__ W2, const float* __restrict__ b2,
        float* __restrict__ out, int n_base, int n, int k) {
    const int b = blockIdx.y, lane = threadIdx.x;
    const int i = blockIdx.x * 64 + lane;
    const float* pb = pos + (size_t)b * n * 3;
    const float* hb = h_base + (size_t)b * n_base * 64;
    const int* selb = sel + (size_t)b * n;
    const float xi = pb[i * 3 + 0], yi = pb[i * 3 + 1], zi = pb[i * 3 + 2];

    __shared__ float a_lds[64 * 64];

    float acc[64];
    #pragma unroll
    for (int c = 0; c < 64; ++c) acc[c] = -__builtin_inff();

    const int* idxp = idx + ((size_t)b * n + i) * k;
    const float* hi = hb + (size_t)selb[i] * 64;
    for (int kk = 0; kk < k; ++kk) {
        const int j = idxp[kk];
        const float xj = pb[j * 3 + 0], yj = pb[j * 3 + 1], zj = pb[j * 3 + 2];
        const float* hj = hb + (size_t)selb[j] * 64;

        float a[64];
        #pragma unroll
        for (int e = 0; e < 64; ++e) a[e] = b1[e];

        for (int d4 = 0; d4 < 16; ++d4) {
            float4 v = *(const float4*)(hi + d4 * 4);
            const float mu[4] = {v.x, v.y, v.z, v.w};
            const float* wr = W1 + (size_t)(d4 * 4) * 64;
            #pragma unroll
            for (int u = 0; u < 4; ++u) {
                #pragma unroll
                for (int e = 0; e < 64; ++e) a[e] = fmaf(mu[u], wr[u * 64 + e], a[e]);
            }
        }
        for (int d4 = 0; d4 < 16; ++d4) {
            float4 v = *(const float4*)(hj + d4 * 4);
            const float mu[4] = {v.x, v.y, v.z, v.w};
            const float* wr = W1 + (size_t)(64 + d4 * 4) * 64;
            #pragma unroll
            for (int u = 0; u < 4; ++u) {
                #pragma unroll
                for (int e = 0; e < 64; ++e) a[e] = fmaf(mu[u], wr[u * 64 + e], a[e]);
            }
        }
        {
            const float mr[3] = {xj - xi, yj - yi, zj - zi};
            #pragma unroll
            for (int d = 0; d < 3; ++d) {
                #pragma unroll
                for (int e = 0; e < 64; ++e) a[e] = fmaf(mr[d], W1[(128 + d) * 64 + e], a[e]);
            }
        }
        __syncthreads();
        #pragma unroll
        for (int e = 0; e < 64; ++e) a_lds[e * 64 + lane] = fmaxf(a[e], 0.f);
        __syncthreads();
        float o[64];
        #pragma unroll
        for (int c = 0; c < 64; ++c) o[c] = b2[c];
        for (int e = 0; e < 64; ++e) {
            float av = a_lds[e * 64 + lane];
            #pragma unroll
            for (int c = 0; c < 64; ++c) o[c] = fmaf(av, W2[e * 64 + c], o[c]);
        }
        #pragma unroll
        for (int c = 0; c < 64; ++c) acc[c] = fmaxf(acc[c], o[c]);
    }
    float* op = out + ((size_t)b * n + i) * 64;
    #pragma unroll
    for (int c = 0; c < 64; ++c) op[c] = fmaxf(acc[c], 0.f);
}

// ---------------------------------------------------------------------------
// Head (round-1 verbatim): global max over points then [64]x[64,6] linear.
// ---------------------------------------------------------------------------
__global__ void __launch_bounds__(64) head_kernel(const float* __restrict__ h,
                                                  const float* __restrict__ Wr,
                                                  const float* __restrict__ br,
                                                  void* __restrict__ out, int n,
                                                  const int* __restrict__ flag) {
    const int b = blockIdx.x, lane = threadIdx.x;
    const float* hb = h + (size_t)b * n * 64;
    float g = -__builtin_inff();
    for (int i = 0; i < n; ++i) g = fmaxf(g, hb[(size_t)i * 64 + lane]);
    __shared__ float gl[64];
    gl[lane] = g;
    __syncthreads();
    if (lane < 6) {
        float o = br[lane];
        #pragma unroll
        for (int c = 0; c < 64; ++c) o = fmaf(gl[c], Wr[c * 6 + lane], o);
        if (*flag) ((__hip_bfloat16*)out)[b * 6 + lane] = __float2bfloat16(o);
        else       ((float*)out)[b * 6 + lane] = o;
    }
}

// ---------------------------------------------------------------------------
extern "C" void kernel_launch(void* const* d_in, const int* in_sizes, int n_in,
                              void* d_out, int out_size, void* d_ws, size_t ws_size,
                              hipStream_t stream) {
    (void)in_sizes; (void)n_in; (void)out_size; (void)ws_size;

    char* w = (char*)d_ws;
    auto alloc = [&](size_t nbytes) -> void* {
        void* p = (void*)w;
        w += (nbytes + 255) & ~(size_t)255;
        return p;
    };

    int*   flag = (int*)alloc(4);
    float* posf = (float*)alloc((size_t)B * N * 3 * 4);
    float* W1a = (float*)alloc(9 * 64 * 4);    float* b1a = (float*)alloc(64 * 4);
    float* W1b = (float*)alloc(64 * 64 * 4);   float* b1b = (float*)alloc(64 * 4);
    float* W2a = (float*)alloc(131 * 64 * 4);  float* b2a = (float*)alloc(64 * 4);
    float* W2b = (float*)alloc(64 * 64 * 4);   float* b2b = (float*)alloc(64 * 4);
    float* W3a = (float*)alloc(131 * 64 * 4);  float* b3a = (float*)alloc(64 * 4);
    float* W3b = (float*)alloc(64 * 64 * 4);   float* b3b = (float*)alloc(64 * 4);
    float* Wr  = (float*)alloc(64 * 6 * 4);    float* br  = (float*)alloc(6 * 4);

    float* h1   = (float*)alloc((size_t)B * N * 64 * 4);        // 16 MB
    float* h2   = (float*)alloc((size_t)B * 1024 * 64 * 4);     // 8 MB
    float* h3   = (float*)alloc((size_t)B * 512 * 64 * 4);      // 4 MB
    int*   idx1 = (int*)alloc((size_t)B * N * 6 * 4);
    int*   idx2 = (int*)alloc((size_t)B * 1024 * 4 * 4);
    int*   idx3 = (int*)alloc((size_t)B * 512 * 3 * 4);
    int*   sel1 = (int*)alloc((size_t)B * 1024 * 4);
    int*   sel2 = (int*)alloc((size_t)B * 512 * 4);
    float* p2   = (float*)alloc((size_t)B * 1024 * 3 * 4);
    float* p3   = (float*)alloc((size_t)B * 512 * 3 * 4);

    // --- dtype detect + convert to fp32 ---
    detect_kernel<<<dim3(1), 256, 0, stream>>>((const unsigned int*)d_in[1], flag);
    ConvParams cp;
    {
        float* wd[15] = {posf, W1a, b1a, W1b, b1b, W2a, b2a, W2b, b2b, W3a, b3a, W3b, b3b, Wr, br};
        const int wi[15] = {1, 3, 4, 5, 6, 7, 8, 9, 10, 11, 12, 13, 14, 15, 16};
        const int wn[15] = {B * N * 3, 576, 64, 4096, 64, 8384, 64, 4096, 64, 8384, 64, 4096, 64, 384, 6};
        for (int q = 0; q < 15; ++q) { cp.s[q].src = d_in[wi[q]]; cp.s[q].dst = wd[q]; cp.s[q].n = wn[q]; }
    }
    convert_kernel<<<dim3((B * N * 3 + 255) / 256, 15), 256, 0, stream>>>(cp, flag);

    // --- FPS chain, isolated (NT=256 measured optimum; spin-poll exchange) ---
    fps_only_kernel<<<dim3(B), 256, 0, stream>>>(posf, sel1, sel2, p2, p3);

    // --- layer 1: knn6 + pointnet (round-1 structure) ---
    knn_kernel<6><<<dim3(N / 256, B), 256, 0, stream>>>(posf, idx1, N);
    pointnet3_kernel<<<dim3(N / 64, B), 64, 0, stream>>>(posf, idx1, W1a, b1a, W1b, b1b, h1, N, 6);

    // --- layer 2: knn4 + pointnet with sel1 indirection ---
    knn_kernel<4><<<dim3(1024 / 256, B), 256, 0, stream>>>(p2, idx2, 1024);
    pointnet64_kernel<<<dim3(1024 / 64, B), 64, 0, stream>>>(h1, p2, sel1, idx2,
                                                             W2a, b2a, W2b, b2b, h2, N, 1024, 4);

    // --- layer 3: knn3 + pointnet with sel2 indirection ---
    knn_kernel<3><<<dim3(512 / 256, B), 256, 0, stream>>>(p3, idx3, 512);
    pointnet64_kernel<<<dim3(512 / 64, B), 64, 0, stream>>>(h2, p3, sel2, idx3,
                                                            W3a, b3a, W3b, b3b, h3, 1024, 512, 3);

    // --- head ---
    head_kernel<<<dim3(B), 64, 0, stream>>>(h3, Wr, br, d_out, 512, flag);
}

// Round 11
// 2086.694 us; speedup vs baseline: 1.1256x; 1.1256x over previous
//
#include <hip/hip_runtime.h>
#include <hip/hip_bf16.h>
#include <math.h>

constexpr int B = 32;
constexpr int N = 2048;

// ---------------------------------------------------------------------------
// dtype sniffer: bf16 vs fp32 (validated rounds 1-10).
// ---------------------------------------------------------------------------
__global__ void detect_kernel(const unsigned int* __restrict__ raw, int* __restrict__ flag) {
    __shared__ int cnt;
    if (threadIdx.x == 0) cnt = 0;
    __syncthreads();
    int c = 0;
    for (int i = threadIdx.x; i < 4096; i += 256) {
        unsigned h = (raw[i] >> 8) & 0x7f;
        if (h >= 0x3a && h <= 0x41) c++;
    }
    atomicAdd(&cnt, c);
    __syncthreads();
    if (threadIdx.x == 0) *flag = (cnt > (4096 * 55) / 100) ? 1 : 0;
}

struct ConvSeg { const void* src; float* dst; int n; };
struct ConvParams { ConvSeg s[15]; };

__global__ void convert_kernel(ConvParams p, const int* __restrict__ flag) {
    const ConvSeg sg = p.s[blockIdx.y];
    int i = blockIdx.x * 256 + threadIdx.x;
    if (i >= sg.n) return;
    if (*flag) sg.dst[i] = __bfloat162float(((const __hip_bfloat16*)sg.src)[i]);
    else       sg.dst[i] = ((const float*)sg.src)[i];
}

// ---------------------------------------------------------------------------
// KNN (round-1 verbatim): k smallest (d2, idx) lexicographic == stable top_k.
// ---------------------------------------------------------------------------
template <int K>
__global__ void __launch_bounds__(256) knn_kernel(const float* __restrict__ pos,
                                                  int* __restrict__ idx_out, int n) {
    #pragma clang fp contract(off)
    const int b = blockIdx.y;
    const int i = blockIdx.x * 256 + threadIdx.x;
    const float* pb = pos + (size_t)b * n * 3;
    const float xi = pb[i * 3 + 0], yi = pb[i * 3 + 1], zi = pb[i * 3 + 2];

    float bd[K];
    int   bi_[K];
    #pragma unroll
    for (int q = 0; q < K; ++q) { bd[q] = __builtin_inff(); bi_[q] = 0x7fffffff; }

    __shared__ float tx[256], ty[256], tz[256];
    for (int t0 = 0; t0 < n; t0 += 256) {
        __syncthreads();
        {
            int j = t0 + threadIdx.x;
            tx[threadIdx.x] = pb[j * 3 + 0];
            ty[threadIdx.x] = pb[j * 3 + 1];
            tz[threadIdx.x] = pb[j * 3 + 2];
        }
        __syncthreads();
        for (int jj = 0; jj < 256; ++jj) {
            float dx = xi - tx[jj], dy = yi - ty[jj], dz = zi - tz[jj];
            float d2 = (dx * dx + dy * dy) + dz * dz;
            int jg = t0 + jj;
            if (d2 < bd[K - 1] || (d2 == bd[K - 1] && jg < bi_[K - 1])) {
                bd[K - 1] = d2; bi_[K - 1] = jg;
                #pragma unroll
                for (int q = K - 1; q > 0; --q) {
                    bool sw = (bd[q] < bd[q - 1]) || (bd[q] == bd[q - 1] && bi_[q] < bi_[q - 1]);
                    if (sw) {
                        float td = bd[q]; bd[q] = bd[q - 1]; bd[q - 1] = td;
                        int   ti = bi_[q]; bi_[q] = bi_[q - 1]; bi_[q - 1] = ti;
                    }
                }
            }
        }
    }
    int* op = idx_out + ((size_t)b * n + i) * K;
    #pragma unroll
    for (int q = 0; q < K; ++q) op[q] = bi_[q];
}

// ---------------------------------------------------------------------------
// Wave-64 max reduce via DPP (pure VALU).
// ---------------------------------------------------------------------------
#define DPP_MAXF(v, ctrl)                                                      \
    (v) = fmaxf((v), __int_as_float(__builtin_amdgcn_update_dpp(               \
        __float_as_int(v), __float_as_int(v), (ctrl), 0xf, 0xf, false)))

// ---------------------------------------------------------------------------
// FPS phase in LDS (exact jnp.argmax semantics, contract-off distances).
// Round-6 configuration — the measured optimum across sync mechanism
// {global-store, barrier, spin-poll}, thread count {128,256,512}, reduce
// {u64-shuffle, DPP+ballot}, and coords-through-reduction. ~1020 cy/iter,
// dominated by the irreducible cross-wave LDS exchange + barrier.
// ---------------------------------------------------------------------------
template <int NPTS>
__device__ __forceinline__ void fps_phase(const float* __restrict__ px,
                                          const float* __restrict__ py,
                                          const float* __restrict__ pz,
                                          int* __restrict__ sel_lds,
                                          unsigned long long* __restrict__ slots,
                                          int m, int t) {
    #pragma clang fp contract(off)
    constexpr int P = NPTS / 256;
    float d[P], ox[P], oy[P], oz[P];
    #pragma unroll
    for (int p = 0; p < P; ++p) {
        const int ii = t * P + p;
        ox[p] = px[ii]; oy[p] = py[ii]; oz[p] = pz[ii];
        d[p] = __builtin_inff();     // iteration 1 update vs point 0 == ref init
    }
    if (t == 0) sel_lds[0] = 0;
    float nx = px[0], ny = py[0], nz = pz[0];

    for (int it = 1; it < m; ++it) {
        float bv = -1.0f; int bix = 0;
        #pragma unroll
        for (int p = 0; p < P; ++p) {
            float dx = ox[p] - nx, dy = oy[p] - ny, dz = oz[p] - nz;
            float dd = (dx * dx + dy * dy) + dz * dz;
            float dn = fminf(d[p], dd);
            d[p] = dn;
            if (dn > bv) { bv = dn; bix = t * P + p; }   // strict > keeps lowest idx
        }
        // wave max (value only, VALU DPP chain)
        float r = bv;
        DPP_MAXF(r, 0x111); DPP_MAXF(r, 0x112); DPP_MAXF(r, 0x114);
        DPP_MAXF(r, 0x118); DPP_MAXF(r, 0x142); DPP_MAXF(r, 0x143);
        const float gmax = __int_as_float(__builtin_amdgcn_readlane(__float_as_int(r), 63));
        // index resolve: lowest lane with bv == gmax == lowest global index
        const unsigned long long msk = __ballot(bv == gmax);
        const int wl = (int)__builtin_ctzll(msk);
        const int widx = __builtin_amdgcn_readlane(bix, wl);
        if ((t & 63) == 0) {
            slots[(it & 1) * 4 + (t >> 6)] =
                ((unsigned long long)(unsigned)__float_as_int(gmax) << 32) |
                (unsigned)(~widx);
        }
        __syncthreads();
        const unsigned long long* sp = slots + (it & 1) * 4;
        unsigned long long k0 = sp[0], k1 = sp[1], k2 = sp[2], k3 = sp[3];
        if (k1 > k0) k0 = k1;
        if (k3 > k2) k2 = k3;
        const unsigned long long kb = (k2 > k0) ? k2 : k0;
        const int g = ~(int)(unsigned)(kb & 0xffffffffULL);
        if (t == 0) sel_lds[it] = g;
        nx = px[g]; ny = py[g]; nz = pz[g];
    }
    __syncthreads();
}

// ---------------------------------------------------------------------------
// FPS-only kernel: 32 blocks x 256 threads (measured optimum), isolated.
// ---------------------------------------------------------------------------
__global__ void __launch_bounds__(256) fps_only_kernel(
        const float* __restrict__ posf, int* __restrict__ sel1, int* __restrict__ sel2,
        float* __restrict__ p2, float* __restrict__ p3) {
    __shared__ float px[2048], py[2048], pz[2048];
    __shared__ float qx[1024], qy[1024], qz[1024];
    __shared__ int sel1_l[1024], sel2_l[512];
    __shared__ unsigned long long slots[8];
    const int t = threadIdx.x;
    const int b = blockIdx.x;

    const float* pb = posf + (size_t)b * N * 3;
    for (int i = t; i < N; i += 256) {
        px[i] = pb[i * 3 + 0]; py[i] = pb[i * 3 + 1]; pz[i] = pb[i * 3 + 2];
    }
    __syncthreads();

    fps_phase<2048>(px, py, pz, sel1_l, slots, 1024, t);

    for (int i = t; i < 1024; i += 256) {
        int s = sel1_l[i];
        qx[i] = px[s]; qy[i] = py[s]; qz[i] = pz[s];
        sel1[(size_t)b * 1024 + i] = s;
    }
    __syncthreads();
    for (int i = t; i < 1024; i += 256) {
        float* pp = p2 + ((size_t)b * 1024 + i) * 3;
        pp[0] = qx[i]; pp[1] = qy[i]; pp[2] = qz[i];
    }

    fps_phase<1024>(qx, qy, qz, sel2_l, slots, 512, t);

    for (int i = t; i < 512; i += 256) {
        int s = sel2_l[i];
        sel2[(size_t)b * 512 + i] = s;
        float* pp = p3 + ((size_t)b * 512 + i) * 3;
        pp[0] = qx[s]; pp[1] = qy[s]; pp[2] = qz[s];
    }
}

// ---------------------------------------------------------------------------
// PointNet layer 1 (round-1 verbatim): thread-per-point, LDS bounce so a[64]
// and o[64] never co-live -> ~108 VGPR, no spill (proven r1/r2/r6).
// ---------------------------------------------------------------------------
__global__ void __launch_bounds__(64) pointnet3_kernel(
        const float* __restrict__ pos, const int* __restrict__ idx,
        const float* __restrict__ W1, const float* __restrict__ b1,
        const float* __restrict__ W2, const float* __restrict__ b2,
        float* __restrict__ out, int n, int k) {
    const int b = blockIdx.y, lane = threadIdx.x;
    const int i = blockIdx.x * 64 + lane;
    const float* pb = pos + (size_t)b * n * 3;
    const float xi = pb[i * 3 + 0], yi = pb[i * 3 + 1], zi = pb[i * 3 + 2];

    __shared__ float a_lds[64 * 64];

    float acc[64];
    #pragma unroll
    for (int c = 0; c < 64; ++c) acc[c] = -__builtin_inff();

    const int* idxp = idx + ((size_t)b * n + i) * k;
    for (int kk = 0; kk < k; ++kk) {
        const int j = idxp[kk];
        const float xj = pb[j * 3 + 0], yj = pb[j * 3 + 1], zj = pb[j * 3 + 2];
        const float mv[9] = {xi, yi, zi, xj, yj, zj, xj - xi, yj - yi, zj - zi};
        float a[64];
        #pragma unroll
        for (int e = 0; e < 64; ++e) a[e] = b1[e];
        #pragma unroll
        for (int d = 0; d < 9; ++d) {
            #pragma unroll
            for (int e = 0; e < 64; ++e) a[e] = fmaf(mv[d], W1[d * 64 + e], a[e]);
        }
        __syncthreads();
        #pragma unroll
        for (int e = 0; e < 64; ++e) a_lds[e * 64 + lane] = fmaxf(a[e], 0.f);
        __syncthreads();
        float o[64];
        #pragma unroll
        for (int c = 0; c < 64; ++c) o[c] = b2[c];
        for (int e = 0; e < 64; ++e) {
            float av = a_lds[e * 64 + lane];
            #pragma unroll
            for (int c = 0; c < 64; ++c) o[c] = fmaf(av, W2[e * 64 + c], o[c]);
        }
        #pragma unroll
        for (int c = 0; c < 64; ++c) acc[c] = fmaxf(acc[c], o[c]);
    }
    float* op = out + ((size_t)b * n + i) * 64;
    #pragma unroll
    for (int c = 0; c < 64; ++c) op[c] = fmaxf(acc[c], 0.f);
}

// ---------------------------------------------------------------------------
// PointNet CHIN=64 (round-1 structure + sel indirection for h reads).
// ---------------------------------------------------------------------------
__global__ void __launch_bounds__(64) pointnet64_kernel(
        const float* __restrict__ h_base, const float* __restrict__ pos,
        const int* __restrict__ sel, const int* __restrict__ idx,
        const float* __restrict__ W1, const float* __restrict__ b1,
        const float* __restrict__ W2, const float* __restrict__ b2,
        float* __restrict__ out, int n_base, int n, int k) {
    const int b = blockIdx.y, lane = threadIdx.x;
    const int i = blockIdx.x * 64 + lane;
    const float* pb = pos + (size_t)b * n * 3;
    const float* hb = h_base + (size_t)b * n_base * 64;
    const int* selb = sel + (size_t)b * n;
    const float xi = pb[i * 3 + 0], yi = pb[i * 3 + 1], zi = pb[i * 3 + 2];

    __shared__ float a_lds[64 * 64];

    float acc[64];
    #pragma unroll
    for (int c = 0; c < 64; ++c) acc[c] = -__builtin_inff();

    const int* idxp = idx + ((size_t)b * n + i) * k;
    const float* hi = hb + (size_t)selb[i] * 64;
    for (int kk = 0; kk < k; ++kk) {
        const int j = idxp[kk];
        const float xj = pb[j * 3 + 0], yj = pb[j * 3 + 1], zj = pb[j * 3 + 2];
        const float* hj = hb + (size_t)selb[j] * 64;

        float a[64];
        #pragma unroll
        for (int e = 0; e < 64; ++e) a[e] = b1[e];

        for (int d4 = 0; d4 < 16; ++d4) {
            float4 v = *(const float4*)(hi + d4 * 4);
            const float mu[4] = {v.x, v.y, v.z, v.w};
            const float* wr = W1 + (size_t)(d4 * 4) * 64;
            #pragma unroll
            for (int u = 0; u < 4; ++u) {
                #pragma unroll
                for (int e = 0; e < 64; ++e) a[e] = fmaf(mu[u], wr[u * 64 + e], a[e]);
            }
        }
        for (int d4 = 0; d4 < 16; ++d4) {
            float4 v = *(const float4*)(hj + d4 * 4);
            const float mu[4] = {v.x, v.y, v.z, v.w};
            const float* wr = W1 + (size_t)(64 + d4 * 4) * 64;
            #pragma unroll
            for (int u = 0; u < 4; ++u) {
                #pragma unroll
                for (int e = 0; e < 64; ++e) a[e] = fmaf(mu[u], wr[u * 64 + e], a[e]);
            }
        }
        {
            const float mr[3] = {xj - xi, yj - yi, zj - zi};
            #pragma unroll
            for (int d = 0; d < 3; ++d) {
                #pragma unroll
                for (int e = 0; e < 64; ++e) a[e] = fmaf(mr[d], W1[(128 + d) * 64 + e], a[e]);
            }
        }
        __syncthreads();
        #pragma unroll
        for (int e = 0; e < 64; ++e) a_lds[e * 64 + lane] = fmaxf(a[e], 0.f);
        __syncthreads();
        float o[64];
        #pragma unroll
        for (int c = 0; c < 64; ++c) o[c] = b2[c];
        for (int e = 0; e < 64; ++e) {
            float av = a_lds[e * 64 + lane];
            #pragma unroll
            for (int c = 0; c < 64; ++c) o[c] = fmaf(av, W2[e * 64 + c], o[c]);
        }
        #pragma unroll
        for (int c = 0; c < 64; ++c) acc[c] = fmaxf(acc[c], o[c]);
    }
    float* op = out + ((size_t)b * n + i) * 64;
    #pragma unroll
    for (int c = 0; c < 64; ++c) op[c] = fmaxf(acc[c], 0.f);
}

// ---------------------------------------------------------------------------
// Head (round-1 verbatim): global max over points then [64]x[64,6] linear.
// ---------------------------------------------------------------------------
__global__ void __launch_bounds__(64) head_kernel(const float* __restrict__ h,
                                                  const float* __restrict__ Wr,
                                                  const float* __restrict__ br,
                                                  void* __restrict__ out, int n,
                                                  const int* __restrict__ flag) {
    const int b = blockIdx.x, lane = threadIdx.x;
    const float* hb = h + (size_t)b * n * 64;
    float g = -__builtin_inff();
    for (int i = 0; i < n; ++i) g = fmaxf(g, hb[(size_t)i * 64 + lane]);
    __shared__ float gl[64];
    gl[lane] = g;
    __syncthreads();
    if (lane < 6) {
        float o = br[lane];
        #pragma unroll
        for (int c = 0; c < 64; ++c) o = fmaf(gl[c], Wr[c * 6 + lane], o);
        if (*flag) ((__hip_bfloat16*)out)[b * 6 + lane] = __float2bfloat16(o);
        else       ((float*)out)[b * 6 + lane] = o;
    }
}

// ---------------------------------------------------------------------------
extern "C" void kernel_launch(void* const* d_in, const int* in_sizes, int n_in,
                              void* d_out, int out_size, void* d_ws, size_t ws_size,
                              hipStream_t stream) {
    (void)in_sizes; (void)n_in; (void)out_size; (void)ws_size;

    char* w = (char*)d_ws;
    auto alloc = [&](size_t nbytes) -> void* {
        void* p = (void*)w;
        w += (nbytes + 255) & ~(size_t)255;
        return p;
    };

    int*   flag = (int*)alloc(4);
    float* posf = (float*)alloc((size_t)B * N * 3 * 4);
    float* W1a = (float*)alloc(9 * 64 * 4);    float* b1a = (float*)alloc(64 * 4);
    float* W1b = (float*)alloc(64 * 64 * 4);   float* b1b = (float*)alloc(64 * 4);
    float* W2a = (float*)alloc(131 * 64 * 4);  float* b2a = (float*)alloc(64 * 4);
    float* W2b = (float*)alloc(64 * 64 * 4);   float* b2b = (float*)alloc(64 * 4);
    float* W3a = (float*)alloc(131 * 64 * 4);  float* b3a = (float*)alloc(64 * 4);
    float* W3b = (float*)alloc(64 * 64 * 4);   float* b3b = (float*)alloc(64 * 4);
    float* Wr  = (float*)alloc(64 * 6 * 4);    float* br  = (float*)alloc(6 * 4);

    float* h1   = (float*)alloc((size_t)B * N * 64 * 4);        // 16 MB
    float* h2   = (float*)alloc((size_t)B * 1024 * 64 * 4);     // 8 MB
    float* h3   = (float*)alloc((size_t)B * 512 * 64 * 4);      // 4 MB
    int*   idx1 = (int*)alloc((size_t)B * N * 6 * 4);
    int*   idx2 = (int*)alloc((size_t)B * 1024 * 4 * 4);
    int*   idx3 = (int*)alloc((size_t)B * 512 * 3 * 4);
    int*   sel1 = (int*)alloc((size_t)B * 1024 * 4);
    int*   sel2 = (int*)alloc((size_t)B * 512 * 4);
    float* p2   = (float*)alloc((size_t)B * 1024 * 3 * 4);
    float* p3   = (float*)alloc((size_t)B * 512 * 3 * 4);

    // --- dtype detect + convert to fp32 ---
    detect_kernel<<<dim3(1), 256, 0, stream>>>((const unsigned int*)d_in[1], flag);
    ConvParams cp;
    {
        float* wd[15] = {posf, W1a, b1a, W1b, b1b, W2a, b2a, W2b, b2b, W3a, b3a, W3b, b3b, Wr, br};
        const int wi[15] = {1, 3, 4, 5, 6, 7, 8, 9, 10, 11, 12, 13, 14, 15, 16};
        const int wn[15] = {B * N * 3, 576, 64, 4096, 64, 8384, 64, 4096, 64, 8384, 64, 4096, 64, 384, 6};
        for (int q = 0; q < 15; ++q) { cp.s[q].src = d_in[wi[q]]; cp.s[q].dst = wd[q]; cp.s[q].n = wn[q]; }
    }
    convert_kernel<<<dim3((B * N * 3 + 255) / 256, 15), 256, 0, stream>>>(cp, flag);

    // --- FPS chain, isolated (NT=256, barrier exchange: measured optimum) ---
    fps_only_kernel<<<dim3(B), 256, 0, stream>>>(posf, sel1, sel2, p2, p3);

    // --- layer 1: knn6 + pointnet (round-1 structure) ---
    knn_kernel<6><<<dim3(N / 256, B), 256, 0, stream>>>(posf, idx1, N);
    pointnet3_kernel<<<dim3(N / 64, B), 64, 0, stream>>>(posf, idx1, W1a, b1a, W1b, b1b, h1, N, 6);

    // --- layer 2: knn4 + pointnet with sel1 indirection ---
    knn_kernel<4><<<dim3(1024 / 256, B), 256, 0, stream>>>(p2, idx2, 1024);
    pointnet64_kernel<<<dim3(1024 / 64, B), 64, 0, stream>>>(h1, p2, sel1, idx2,
                                                             W2a, b2a, W2b, b2b, h2, N, 1024, 4);

    // --- layer 3: knn3 + pointnet with sel2 indirection ---
    knn_kernel<3><<<dim3(512 / 256, B), 256, 0, stream>>>(p3, idx3, 512);
    pointnet64_kernel<<<dim3(512 / 64, B), 64, 0, stream>>>(h2, p3, sel2, idx3,
                                                            W3a, b3a, W3b, b3b, h3, 1024, 512, 3);

    // --- head ---
    head_kernel<<<dim3(B), 64, 0, stream>>>(h3, Wr, br, d_out, 512, flag);
}